// Round 7
// baseline (1519.584 us; speedup 1.0000x reference)
//
#include <hip/hip_runtime.h>
#include <stdint.h>

// LSTM_Trend: B=256, T=512, F=64, H=512, P=24.
// Persistent kernel: 256 WGs x 256 threads (1/CU) = 16 batch-groups (16 rows)
// x 16 hidden-groups (32 h-units = 128 gate cols). Weights register-resident
// as MFMA B-fragments (2 subtiles x 18 K-iters = 144 VGPRs); one A-frag feeds
// 2 MFMAs. BARRIER-FREE exchange: each h dword is stored as an aligned 8-byte
// (h,tag) pair via global_store_dwordx2 sc0 sc1 (L1/L2-bypass, L3-coherent);
// consumers retry-load chunks until tag == step. No flags, no atomics, no
// fences, no cache maintenance, 2 syncthreads/step. Double-buffer WAR safety
// is inductive through the tag chain (writer of tag t+3 has observed all tags
// t+2, whose producers had fully consumed t+1). ws 0xAA poison never matches
// a tag (1..512), so no workspace init is needed at all.

namespace {
constexpr int T_STEPS = 512;
constexpr int FEA  = 64;
constexpr int HID  = 512;
constexpr int KTOT = HID + FEA;   // 576
constexpr int KPAD = KTOT + 8;    // 584 bf16 = 1168 B rows (16B skew)
constexpr int NKI  = KTOT / 32;   // 18 K-iterations
constexpr int GSTR = 132;         // gates LDS row stride (floats)
constexpr int RPG  = 16;          // batch rows per group
constexpr size_t HBUF_DW = 256ull * 512;   // dwords per buffer (h+tag pairs)

typedef __bf16   bf16x8 __attribute__((ext_vector_type(8)));
typedef uint16_t u16x8  __attribute__((ext_vector_type(8)));
typedef float    f32x4  __attribute__((ext_vector_type(4)));
typedef uint32_t u32x4  __attribute__((ext_vector_type(4)));
typedef uint32_t u32x2  __attribute__((ext_vector_type(2)));

union V8 { u16x8 u; bf16x8 b; u32x4 q; };

__device__ __forceinline__ float bf2f(uint16_t u) {
  union { uint32_t i; float f; } v; v.i = (uint32_t)u << 16; return v.f;
}
__device__ __forceinline__ uint16_t f2bf(float f) {
  union { float f; uint32_t i; } v; v.f = f;
  uint32_t x = v.i;
  return (uint16_t)((x + 0x7FFFu + ((x >> 16) & 1u)) >> 16);  // RNE
}
__device__ __forceinline__ float sigmoid_f(float x) {
  return 1.0f / (1.0f + __expf(-x));
}
__device__ __forceinline__ float tanh_f(float x) {
  float e = __expf(-2.0f * fabsf(x));
  float t = (1.0f - e) / (1.0f + e);
  return copysignf(t, x);
}
__device__ __forceinline__ bf16x8 load8(const void* base, size_t elem_off,
                                        bool fp32m) {
  V8 r;
  if (fp32m) {
    const float* p = (const float*)base + elem_off;
#pragma unroll
    for (int i = 0; i < 8; ++i) r.u[i] = f2bf(p[i]);
  } else {
    r.q = *(const u32x4*)((const uint16_t*)base + elem_off);
  }
  return r.b;
}
__device__ __forceinline__ float loadf(const void* base, int idx, bool fp32m) {
  return fp32m ? ((const float*)base)[idx] : bf2f(((const uint16_t*)base)[idx]);
}

// ---- explicit L3-coherent (L1/L2-bypass) memory ops -----------------------
__device__ __forceinline__ u32x4 ld128_sc01(const uint32_t* p) {
  u32x4 v;
  asm volatile("global_load_dwordx4 %0, %1, off sc0 sc1"
               : "=v"(v) : "v"(p) : "memory");
  return v;
}
__device__ __forceinline__ void st64_sc01(uint32_t* p, uint32_t lo, uint32_t hi) {
  u32x2 v; v[0] = lo; v[1] = hi;
  asm volatile("global_store_dwordx2 %0, %1, off sc0 sc1"
               :: "v"(p), "v"(v) : "memory");
}
__device__ __forceinline__ void waitcnt_vm0() {
  asm volatile("s_waitcnt vmcnt(0)" ::: "memory");
}
} // namespace

__global__ __launch_bounds__(256, 1) void lstm_persistent(
    const void* __restrict__ x,      // [256][512][64]
    const void* __restrict__ W_ih,   // [2048][64]
    const void* __restrict__ W_hh,   // [2048][512]
    const void* __restrict__ b_ih,   // [2048]
    const void* __restrict__ b_hh,   // [2048]
    const void* __restrict__ W_fc,   // [1536][512]
    const void* __restrict__ b_fc,   // [1536]
    void* __restrict__ out,          // [256][1536]
    uint32_t* __restrict__ hbuf)     // [2][256][256] (h dword, tag) pairs
{
  __shared__ uint16_t Als[RPG * KPAD];   // A tile: [h_{t-1} | x_t], 16 rows
  __shared__ float    Gls[RPG * GSTR];   // gate pre-activations, fp32
  __shared__ int      sflag;

  const int tid = threadIdx.x;
  const int wv  = tid >> 6;              // wave 0..3
  const int ln  = tid & 63;
  const int nl  = ln & 15;               // MFMA m/n lane index
  const int kq  = ln >> 4;               // MFMA k-quad
  const int bg  = blockIdx.x & 15;       // batch group
  const int wgi = blockIdx.x >> 4;       // hidden group 0..15
  const int r0  = bg * RPG;              // first batch row of this group

  // ---- dtype sniff (block-uniform): fp32 read as bf16 -> huge exponents
  if (tid == 0) sflag = 0;
  __syncthreads();
  {
    float a = fabsf(bf2f(((const uint16_t*)b_ih)[tid]));
    if (a > 1.0f) atomicOr(&sflag, 1);
  }
  __syncthreads();
  const bool fp32m = (sflag != 0);

  // wave owns cols [wv*32, wv*32+32) as two 16-col subtiles sharing one A-frag
  // col = 4*unit + gate (i,f,g,o of one h-unit in 4 adjacent cols)
  bf16x8 breg[2][NKI];
  float  bias[2];
#pragma unroll
  for (int s = 0; s < 2; ++s) {
    int col  = wv * 32 + s * 16 + nl;
    int gate = col & 3;
    int unit = col >> 2;
    int gcol = gate * HID + wgi * 32 + unit;
#pragma unroll
    for (int kk = 0; kk < NKI; ++kk) {
      int k0 = kk * 32 + kq * 8;
      if (k0 < HID)
        breg[s][kk] = load8(W_hh, (size_t)gcol * HID + k0, fp32m);
      else
        breg[s][kk] = load8(W_ih, (size_t)gcol * FEA + (k0 - HID), fp32m);
    }
    bias[s] = loadf(b_ih, gcol, fp32m) + loadf(b_hh, gcol, fp32m);
  }

  // activation ownership: row ar (0..15), units au, au+1 -> (h,tag) pair
  const int ar  = tid >> 4;
  const int l16 = tid & 15;
  const int au  = l16 * 2;
  // pair index within a row = wgi*16 + l16; row stride = 512 dwords
  uint32_t* const hpair = hbuf + ((size_t)(r0 + ar) * 512
                                  + (size_t)(wgi * 16 + l16) * 2);
  float c0 = 0.0f, c1 = 0.0f;

  const int srow = tid >> 4;             // staging row (== ar)
  uint16_t* Ar = &Als[srow * KPAD];

  // ---- prologue: h_0 = 0 in LDS, stage x_0 ----
  {
    u32x4 z = {0, 0, 0, 0};
#pragma unroll
    for (int i = 0; i < 4; ++i) *(u32x4*)&Ar[(l16 + 16 * i) * 8] = z;
    int xo = l16 * 4;
    size_t off = (size_t)(r0 + srow) * (T_STEPS * FEA) + xo;
    uint2 w;
    if (fp32m) {
      const float4 xv = *(const float4*)((const float*)x + off);
      w.x = (uint32_t)f2bf(xv.x) | ((uint32_t)f2bf(xv.y) << 16);
      w.y = (uint32_t)f2bf(xv.z) | ((uint32_t)f2bf(xv.w) << 16);
    } else {
      w = *(const uint2*)((const uint16_t*)x + off);
    }
    *(uint2*)&Ar[HID + xo] = w;
  }

  for (int t = 0; t < T_STEPS; ++t) {
    __syncthreads();                     // S1: A tile staged

    // ---- gates = A @ W^T + bias: 18 K-steps, 1 A-frag -> 2 MFMAs ----
    f32x4 acc0, acc1;
    acc0[0] = bias[0]; acc0[1] = bias[0]; acc0[2] = bias[0]; acc0[3] = bias[0];
    acc1[0] = bias[1]; acc1[1] = bias[1]; acc1[2] = bias[1]; acc1[3] = bias[1];
#pragma unroll
    for (int kk = 0; kk < NKI; ++kk) {
      bf16x8 a = *(const bf16x8*)&Als[nl * KPAD + kk * 32 + kq * 8];
      acc0 = __builtin_amdgcn_mfma_f32_16x16x32_bf16(a, breg[0][kk], acc0, 0, 0, 0);
      acc1 = __builtin_amdgcn_mfma_f32_16x16x32_bf16(a, breg[1][kk], acc1, 0, 0, 0);
    }
#pragma unroll
    for (int r = 0; r < 4; ++r) {
      Gls[(kq * 4 + r) * GSTR + wv * 32 + nl]      = acc0[r];
      Gls[(kq * 4 + r) * GSTR + wv * 32 + 16 + nl] = acc1[r];
    }
    __syncthreads();                     // S2: gates ready, Als free

    // ---- activations, cell update, tagged (h,tag) 8B store -> L3 ----
    const uint32_t tg = (uint32_t)(t + 1);
    {
      const f32x4* gp = (const f32x4*)&Gls[ar * GSTR + au * 4];
      f32x4 ga = gp[0], gb = gp[1];
      c0 = sigmoid_f(ga[1]) * c0 + sigmoid_f(ga[0]) * tanh_f(ga[2]);
      float h0 = sigmoid_f(ga[3]) * tanh_f(c0);
      c1 = sigmoid_f(gb[1]) * c1 + sigmoid_f(gb[0]) * tanh_f(gb[2]);
      float h1 = sigmoid_f(gb[3]) * tanh_f(c1);
      uint32_t hp = (uint32_t)f2bf(h0) | ((uint32_t)f2bf(h1) << 16);
      st64_sc01(hpair + ((size_t)(tg & 1)) * HBUF_DW, hp, tg);
    }

    // ---- stage step t+1: x load (overlap) + tagged h retry-stage ----
    uint2 xw;
    const bool havex = (t + 1 < T_STEPS);
    if (havex) {
      int xo = l16 * 4;
      size_t off = (size_t)(r0 + srow) * (T_STEPS * FEA)
                   + (size_t)(t + 1) * FEA + xo;
      if (fp32m) {
        const float4 xv = *(const float4*)((const float*)x + off);
        xw.x = (uint32_t)f2bf(xv.x) | ((uint32_t)f2bf(xv.y) << 16);
        xw.y = (uint32_t)f2bf(xv.z) | ((uint32_t)f2bf(xv.w) << 16);
      } else {
        xw = *(const uint2*)((const uint16_t*)x + off);
      }
    }
    {
      const uint32_t* src = hbuf + ((size_t)(tg & 1)) * HBUF_DW
                            + (size_t)(r0 + srow) * 512;
      uint32_t pend = 0xFu;              // 4 chunks of 4 h-dwords each
      u32x4 a0[4], a1[4];
      do {
#pragma unroll
        for (int i = 0; i < 4; ++i) {
          if (pend & (1u << i)) {
            const uint32_t* p = src + (size_t)(l16 + 16 * i) * 8;
            a0[i] = ld128_sc01(p);
            a1[i] = ld128_sc01(p + 4);
          }
        }
        waitcnt_vm0();
#pragma unroll
        for (int i = 0; i < 4; ++i) {
          if (pend & (1u << i)) {
            if (a0[i][1] == tg && a0[i][3] == tg &&
                a1[i][1] == tg && a1[i][3] == tg) {
              u32x4 h4;
              h4[0] = a0[i][0]; h4[1] = a0[i][2];
              h4[2] = a1[i][0]; h4[3] = a1[i][2];
              *(u32x4*)&Ar[(l16 + 16 * i) * 8] = h4;
              pend &= ~(1u << i);
            }
          }
        }
        if (pend) __builtin_amdgcn_s_sleep(1);
      } while (pend);
    }
    if (havex) *(uint2*)&Ar[HID + l16 * 4] = xw;
  }

  __syncthreads();                       // h_T (tag 512) staged in Als

  // ---- FC head: out = h_T @ W_fc^T + b_fc  (h_T read from LDS) ----
  int gwave = wgi * 4 + wv;              // 0..63 within the batch group
  for (int tile = gwave; tile < 96; tile += 64) {
    int n = tile * 16 + nl;              // out column
    float bs = loadf(b_fc, n, fp32m);
    f32x4 acc; acc[0] = bs; acc[1] = bs; acc[2] = bs; acc[3] = bs;
#pragma unroll
    for (int kk = 0; kk < 16; ++kk) {
      int k0 = kk * 32 + kq * 8;
      bf16x8 a = *(const bf16x8*)&Als[nl * KPAD + k0];
      bf16x8 b = load8(W_fc, (size_t)n * HID + k0, fp32m);
      acc = __builtin_amdgcn_mfma_f32_16x16x32_bf16(a, b, acc, 0, 0, 0);
    }
#pragma unroll
    for (int r = 0; r < 4; ++r) {
      int row = r0 + kq * 4 + r;
      if (fp32m) ((float*)out)[(size_t)row * 1536 + n] = acc[r];
      else       ((uint16_t*)out)[(size_t)row * 1536 + n] = f2bf(acc[r]);
    }
  }
}

extern "C" void kernel_launch(void* const* d_in, const int* in_sizes, int n_in,
                              void* d_out, int out_size, void* d_ws, size_t ws_size,
                              hipStream_t stream) {
  const void* x    = d_in[0];
  const void* W_ih = d_in[1];
  const void* W_hh = d_in[2];
  const void* b_ih = d_in[3];
  const void* b_hh = d_in[4];
  const void* W_fc = d_in[5];
  const void* b_fc = d_in[6];
  uint32_t* hbuf = (uint32_t*)d_ws;   // 0xAA poison never matches tags 1..512

  lstm_persistent<<<dim3(256), dim3(256), 0, stream>>>(
      x, W_ih, W_hh, b_ih, b_hh, W_fc, b_fc, d_out, hbuf);
}

// Round 8
// 1515.460 us; speedup vs baseline: 1.0027x; 1.0027x over previous
//
#include <hip/hip_runtime.h>
#include <stdint.h>

// LSTM_Trend: B=256, T=512, F=64, H=512, P=24.
// Persistent kernel: 256 WGs x 256 threads (1/CU) = 16 batch-groups (16 rows)
// x 16 hidden-groups (32 h-units = 128 gate cols). Weights register-resident
// as MFMA B-fragments (2 subtiles x 18 K-iters); one A-frag feeds 2 MFMAs.
// KEY (round 8): h exchange + flags are produced with fire-and-forget
// global_atomic_swap sc1 (far atomic, executes AT the L3/MALL -> line stays
// L3-resident), consumed with sc0sc1 loads (L1/L2-bypass -> L3 hit ~450cyc).
// Plain sc1 stores proved write-through-no-allocate (r6/r7: WRITE_SIZE==h
// volume, h loads refetched from HBM at ~900cyc). Barrier: per-WG flag dwords
// in one 64B line; producer swaps flag=t+1 after vmcnt(0) h-drain; lanes 0..15
// poll own dword. x is register-prefetched 2 steps ahead.

namespace {
constexpr int T_STEPS = 512;
constexpr int FEA  = 64;
constexpr int HID  = 512;
constexpr int KTOT = HID + FEA;   // 576
constexpr int KPAD = KTOT + 8;    // 584 bf16 = 1168 B rows (16B skew)
constexpr int NKI  = KTOT / 32;   // 18 K-iterations
constexpr int GSTR = 132;         // gates LDS row stride (floats)
constexpr int RPG  = 16;          // batch rows per group
constexpr size_t HBUF_HALF = 256ull * 512;          // bf16 elems per buffer
constexpr size_t BAR_OFF   = 2 * HBUF_HALF * 2;     // byte offset of flags

typedef __bf16   bf16x8 __attribute__((ext_vector_type(8)));
typedef uint16_t u16x8  __attribute__((ext_vector_type(8)));
typedef float    f32x4  __attribute__((ext_vector_type(4)));
typedef uint32_t u32x4  __attribute__((ext_vector_type(4)));

union V8 { u16x8 u; bf16x8 b; u32x4 q; };

__device__ __forceinline__ float bf2f(uint16_t u) {
  union { uint32_t i; float f; } v; v.i = (uint32_t)u << 16; return v.f;
}
__device__ __forceinline__ uint16_t f2bf(float f) {
  union { float f; uint32_t i; } v; v.f = f;
  uint32_t x = v.i;
  return (uint16_t)((x + 0x7FFFu + ((x >> 16) & 1u)) >> 16);  // RNE
}
__device__ __forceinline__ float sigmoid_f(float x) {
  return 1.0f / (1.0f + __expf(-x));
}
__device__ __forceinline__ float tanh_f(float x) {
  float e = __expf(-2.0f * fabsf(x));
  float t = (1.0f - e) / (1.0f + e);
  return copysignf(t, x);
}
__device__ __forceinline__ bf16x8 load8(const void* base, size_t elem_off,
                                        bool fp32m) {
  V8 r;
  if (fp32m) {
    const float* p = (const float*)base + elem_off;
#pragma unroll
    for (int i = 0; i < 8; ++i) r.u[i] = f2bf(p[i]);
  } else {
    r.q = *(const u32x4*)((const uint16_t*)base + elem_off);
  }
  return r.b;
}
__device__ __forceinline__ float loadf(const void* base, int idx, bool fp32m) {
  return fp32m ? ((const float*)base)[idx] : bf2f(((const uint16_t*)base)[idx]);
}

// ---- explicit L3-coherent (L1/L2-bypass) memory ops -----------------------
__device__ __forceinline__ uint32_t ld32_sc01(const uint32_t* p) {
  uint32_t v;
  asm volatile("global_load_dword %0, %1, off sc0 sc1"
               : "=v"(v) : "v"(p) : "memory");
  return v;
}
__device__ __forceinline__ u32x4 ld128_sc01(const uint32_t* p) {
  u32x4 v;
  asm volatile("global_load_dwordx4 %0, %1, off sc0 sc1"
               : "=v"(v) : "v"(p) : "memory");
  return v;
}
// fire-and-forget swap: far atomic executed AT the L3 -> line stays resident
__device__ __forceinline__ void swap32_sc1(uint32_t* p, uint32_t v) {
  asm volatile("global_atomic_swap %0, %1, off sc1"
               :: "v"(p), "v"(v) : "memory");
}
__device__ __forceinline__ void waitcnt_vm0() {
  asm volatile("s_waitcnt vmcnt(0)" ::: "memory");
}
} // namespace

__global__ __launch_bounds__(256, 1) void lstm_persistent(
    const void* __restrict__ x,      // [256][512][64]
    const void* __restrict__ W_ih,   // [2048][64]
    const void* __restrict__ W_hh,   // [2048][512]
    const void* __restrict__ b_ih,   // [2048]
    const void* __restrict__ b_hh,   // [2048]
    const void* __restrict__ W_fc,   // [1536][512]
    const void* __restrict__ b_fc,   // [1536]
    void* __restrict__ out,          // [256][1536]
    uint16_t* __restrict__ hbuf,     // [2][256][512] bf16 (workspace)
    uint32_t* __restrict__ bar)      // 16 groups x 16 flag dwords (64B/line)
{
  __shared__ uint16_t Als[RPG * KPAD];   // A tile: [h_{t-1} | x_t], 16 rows
  __shared__ float    Gls[RPG * GSTR];   // gate pre-activations, fp32
  __shared__ int      sflag;

  const int tid = threadIdx.x;
  const int wv  = tid >> 6;              // wave 0..3
  const int ln  = tid & 63;
  const int nl  = ln & 15;               // MFMA m/n lane index
  const int kq  = ln >> 4;               // MFMA k-quad
  const int bg  = blockIdx.x & 15;       // batch group
  const int wgi = blockIdx.x >> 4;       // hidden group 0..15
  const int r0  = bg * RPG;              // first batch row of this group

  // ---- dtype sniff (block-uniform): fp32 read as bf16 -> huge exponents
  if (tid == 0) sflag = 0;
  __syncthreads();
  {
    float a = fabsf(bf2f(((const uint16_t*)b_ih)[tid]));
    if (a > 1.0f) atomicOr(&sflag, 1);
  }
  __syncthreads();
  const bool fp32m = (sflag != 0);

  // wave owns cols [wv*32, wv*32+32) as two 16-col subtiles sharing one A-frag
  // col = 4*unit + gate (i,f,g,o of one h-unit in 4 adjacent cols)
  bf16x8 breg[2][NKI];
  float  bias[2];
#pragma unroll
  for (int s = 0; s < 2; ++s) {
    int col  = wv * 32 + s * 16 + nl;
    int gate = col & 3;
    int unit = col >> 2;
    int gcol = gate * HID + wgi * 32 + unit;
#pragma unroll
    for (int kk = 0; kk < NKI; ++kk) {
      int k0 = kk * 32 + kq * 8;
      if (k0 < HID)
        breg[s][kk] = load8(W_hh, (size_t)gcol * HID + k0, fp32m);
      else
        breg[s][kk] = load8(W_ih, (size_t)gcol * FEA + (k0 - HID), fp32m);
    }
    bias[s] = loadf(b_ih, gcol, fp32m) + loadf(b_hh, gcol, fp32m);
  }

  // activation ownership: row ar (0..15), units au, au+1
  const int ar  = tid >> 4;
  const int l16 = tid & 15;
  const int au  = l16 * 2;
  const int hdw = (r0 + ar) * 256 + wgi * 16 + l16;   // packed h dword index
  float c0 = 0.0f, c1 = 0.0f;

  const int srow = tid >> 4;             // staging row (== ar)
  uint16_t* Ar = &Als[srow * KPAD];

  uint32_t* flags = bar + bg * 16;       // this group's 64B flag line

  const size_t xrow = (size_t)(r0 + srow) * (T_STEPS * FEA) + l16 * 4;

  // ---- prologue: h_0 = 0 in LDS, stage x_0, prefetch x_1 ----
  uint4 xr;                              // raw x for step t+1 (fp32: 4 floats)
  {
    u32x4 z = {0, 0, 0, 0};
#pragma unroll
    for (int i = 0; i < 4; ++i) *(u32x4*)&Ar[(l16 + 16 * i) * 8] = z;
    uint2 w;
    if (fp32m) {
      const float4 xv = *(const float4*)((const float*)x + xrow);
      w.x = (uint32_t)f2bf(xv.x) | ((uint32_t)f2bf(xv.y) << 16);
      w.y = (uint32_t)f2bf(xv.z) | ((uint32_t)f2bf(xv.w) << 16);
      xr = *(const uint4*)((const float*)x + xrow + FEA);      // x_1 raw
    } else {
      w = *(const uint2*)((const uint16_t*)x + xrow);
      const uint2 n = *(const uint2*)((const uint16_t*)x + xrow + FEA);
      xr.x = n.x; xr.y = n.y;
    }
    *(uint2*)&Ar[HID + l16 * 4] = w;
  }

  for (int t = 0; t < T_STEPS; ++t) {
    __syncthreads();                     // S1: A tile staged

    // ---- gates = A @ W^T + bias: 18 K-steps, 1 A-frag -> 2 MFMAs ----
    f32x4 acc0, acc1;
    acc0[0] = bias[0]; acc0[1] = bias[0]; acc0[2] = bias[0]; acc0[3] = bias[0];
    acc1[0] = bias[1]; acc1[1] = bias[1]; acc1[2] = bias[1]; acc1[3] = bias[1];
#pragma unroll
    for (int kk = 0; kk < NKI; ++kk) {
      bf16x8 a = *(const bf16x8*)&Als[nl * KPAD + kk * 32 + kq * 8];
      acc0 = __builtin_amdgcn_mfma_f32_16x16x32_bf16(a, breg[0][kk], acc0, 0, 0, 0);
      acc1 = __builtin_amdgcn_mfma_f32_16x16x32_bf16(a, breg[1][kk], acc1, 0, 0, 0);
    }
#pragma unroll
    for (int r = 0; r < 4; ++r) {
      Gls[(kq * 4 + r) * GSTR + wv * 32 + nl]      = acc0[r];
      Gls[(kq * 4 + r) * GSTR + wv * 32 + 16 + nl] = acc1[r];
    }
    __syncthreads();                     // S2: gates ready, Als free

    // ---- activations, cell update, h published via far-atomic swap ----
    {
      const f32x4* gp = (const f32x4*)&Gls[ar * GSTR + au * 4];
      f32x4 ga = gp[0], gb = gp[1];
      c0 = sigmoid_f(ga[1]) * c0 + sigmoid_f(ga[0]) * tanh_f(ga[2]);
      float h0 = sigmoid_f(ga[3]) * tanh_f(c0);
      c1 = sigmoid_f(gb[1]) * c1 + sigmoid_f(gb[0]) * tanh_f(gb[2]);
      float h1 = sigmoid_f(gb[3]) * tanh_f(c1);
      uint32_t hp = (uint32_t)f2bf(h0) | ((uint32_t)f2bf(h1) << 16);
      uint32_t* hw = (uint32_t*)(hbuf + (size_t)((t + 1) & 1) * HBUF_HALF);
      swap32_sc1(hw + hdw, hp);          // L3-resident publish
    }
    waitcnt_vm0();                       // swap ACKed at L3
    __syncthreads();                     // S3: whole WG's h published

    // ---- publish flag, stage x_{t+1} from regs + prefetch x_{t+2}, poll ----
    if (tid == 0) swap32_sc1(flags + wgi, (uint32_t)(t + 1));
    if (t + 1 < T_STEPS) {
      uint2 w;
      if (fp32m) {
        const float* xf = (const float*)&xr;
        w.x = (uint32_t)f2bf(xf[0]) | ((uint32_t)f2bf(xf[1]) << 16);
        w.y = (uint32_t)f2bf(xf[2]) | ((uint32_t)f2bf(xf[3]) << 16);
      } else {
        w.x = xr.x; w.y = xr.y;
      }
      *(uint2*)&Ar[HID + l16 * 4] = w;
      if (t + 2 < T_STEPS) {             // prefetch x_{t+2} into registers
        size_t off = xrow + (size_t)(t + 2) * FEA;
        if (fp32m) {
          xr = *(const uint4*)((const float*)x + off);
        } else {
          const uint2 n = *(const uint2*)((const uint16_t*)x + off);
          xr.x = n.x; xr.y = n.y;
        }
      }
    }
    if (tid < 16) {                      // lane i waits on WG i's flag
      const uint32_t* fp = flags + tid;
      uint32_t target = (uint32_t)(t + 1);
      for (;;) {
        uint32_t c = ld32_sc01(fp);
        waitcnt_vm0();
        if (c >= target) break;
      }
    }
    __syncthreads();                     // S4: barrier passed

    // ---- load h_{t+1} (sc0sc1 -> L3 hit) into LDS ----
    if (t + 1 < T_STEPS) {
      const uint32_t* src =
          (const uint32_t*)(hbuf + (size_t)((t + 1) & 1) * HBUF_HALF)
          + (size_t)(r0 + srow) * 256;
      u32x4 v0 = ld128_sc01(src + (l16 + 0)  * 4);
      u32x4 v1 = ld128_sc01(src + (l16 + 16) * 4);
      u32x4 v2 = ld128_sc01(src + (l16 + 32) * 4);
      u32x4 v3 = ld128_sc01(src + (l16 + 48) * 4);
      waitcnt_vm0();
      *(u32x4*)&Ar[(l16 + 0)  * 8] = v0;
      *(u32x4*)&Ar[(l16 + 16) * 8] = v1;
      *(u32x4*)&Ar[(l16 + 32) * 8] = v2;
      *(u32x4*)&Ar[(l16 + 48) * 8] = v3;
    }
  }

  // ---- FC head: out = h_T @ W_fc^T + b_fc  (h_T is in buffer 0) ----
  const uint32_t* hn = (const uint32_t*)hbuf;
  int gwave = wgi * 4 + wv;              // 0..63 within the batch group
  for (int tile = gwave; tile < 96; tile += 64) {
    int n = tile * 16 + nl;              // out column
    float bs = loadf(b_fc, n, fp32m);
    f32x4 acc; acc[0] = bs; acc[1] = bs; acc[2] = bs; acc[3] = bs;
#pragma unroll
    for (int kk = 0; kk < 16; ++kk) {
      int k0 = kk * 32 + kq * 8;
      V8 av;
      av.q = ld128_sc01(hn + (size_t)(r0 + nl) * 256 + (k0 >> 1));
      bf16x8 b = load8(W_fc, (size_t)n * HID + k0, fp32m);
      waitcnt_vm0();
      acc = __builtin_amdgcn_mfma_f32_16x16x32_bf16(av.b, b, acc, 0, 0, 0);
    }
#pragma unroll
    for (int r = 0; r < 4; ++r) {
      int row = r0 + kq * 4 + r;
      if (fp32m) ((float*)out)[(size_t)row * 1536 + n] = acc[r];
      else       ((uint16_t*)out)[(size_t)row * 1536 + n] = f2bf(acc[r]);
    }
  }
}

extern "C" void kernel_launch(void* const* d_in, const int* in_sizes, int n_in,
                              void* d_out, int out_size, void* d_ws, size_t ws_size,
                              hipStream_t stream) {
  const void* x    = d_in[0];
  const void* W_ih = d_in[1];
  const void* W_hh = d_in[2];
  const void* b_ih = d_in[3];
  const void* b_hh = d_in[4];
  const void* W_fc = d_in[5];
  const void* b_fc = d_in[6];
  uint16_t* hbuf = (uint16_t*)d_ws;
  uint32_t* bar  = (uint32_t*)((char*)d_ws + BAR_OFF);

  // flags must start at 0 (ws is poisoned 0xAA each call; 0xAAAAAAAA >= any
  // target would make polls pass early)
  hipMemsetAsync((void*)bar, 0, 16 * 16 * sizeof(uint32_t), stream);

  lstm_persistent<<<dim3(256), dim3(256), 0, stream>>>(
      x, W_ih, W_hh, b_ih, b_hh, W_fc, b_fc, d_out, hbuf, bar);
}